// Round 14
// baseline (196.218 us; speedup 1.0000x reference)
//
#include <hip/hip_runtime.h>

// Attention_72902774882333 — R23: attn block width 8 -> 16 waves (1024 thr,
// 512 q-rows/block). Wave-width trend is monotone: R17 2w=107, R16 4w=96.5,
// R22 8w=91.2 — barriers/staging amortize over 2x q-rows each doubling.
// Grid (8,16,2)=256 blocks = 1/CU; 16 waves @ ~108 unified regs = 4/SIMD fits.
// Staging: waves 0-7 stage K, 8-15 stage V (1 gload16/wave). Epilogue: 4
// phases of 128 rows through the same [128][72] overlay. Everything else
// byte-identical to R22 (total 195.9, best). B=4, C=256, N=4096, H=4, DK=64.

#define BDIM 4
#define CDIM 256
#define NDIM 4096
#define HDIM 4
#define DKDIM 64
#define NQ   (BDIM * HDIM * NDIM)       // 65536
#define NSPLIT 2
#define KPERZ (NDIM / NSPLIT)           // 2048 keys per split
#define QSCALE 0.18033688011112042f     // log2(e)/8
#define WSZ (CDIM * CDIM)               // 65536 elems per weight matrix

typedef __bf16 bf16x8 __attribute__((ext_vector_type(8)));
typedef float f32x4 __attribute__((ext_vector_type(4)));
typedef short s16x4 __attribute__((ext_vector_type(4)));
typedef unsigned short u16;
typedef unsigned int u32;

__device__ __forceinline__ u16 f2bf(float f) {
  union { __bf16 h; u16 s; } u; u.h = (__bf16)f; return u.s;
}
__device__ __forceinline__ float bf2f(u16 v) {
  union { u32 u; float f; } x; x.u = (u32)v << 16; return x.f;
}
__device__ __forceinline__ u32 pk2(float a, float b) {
  return (u32)f2bf(a) | ((u32)f2bf(b) << 16);
}
__device__ __forceinline__ void gload16(const u16* g, u16* l) {
  __builtin_amdgcn_global_load_lds(
      (const __attribute__((address_space(1))) void*)g,
      (__attribute__((address_space(3))) void*)l, 16, 0, 0);
}

// ---------------- weight conversion: fp32 -> bf16, once ----------------
// wb layout: [4][WSZ] = wq(scaled), wk, wv, wp. Grid (32, 4).
__global__ __launch_bounds__(256) void wconv_kernel(
    const float* __restrict__ wq, const float* __restrict__ wk,
    const float* __restrict__ wv, const float* __restrict__ wp,
    u16* __restrict__ wb)
{
  const int a = blockIdx.y;
  const float* src = (a == 0) ? wq : (a == 1) ? wk : (a == 2) ? wv : wp;
  const float sc = (a == 0) ? QSCALE : 1.0f;
  const int i = (blockIdx.x * 256 + threadIdx.x) * 8;
  const float4 v0 = *(const float4*)(src + i);
  const float4 v1 = *(const float4*)(src + i + 4);
  union { u32 p[4]; uint4 q; } o;
  o.p[0] = pk2(v0.x * sc, v0.y * sc);
  o.p[1] = pk2(v0.z * sc, v0.w * sc);
  o.p[2] = pk2(v1.x * sc, v1.y * sc);
  o.p[3] = pk2(v1.z * sc, v1.w * sc);
  *(uint4*)(wb + (size_t)a * WSZ + i) = o.q;
}

// ---------------- x transpose: fp32 [b][c][n] -> bf16 [b][n][256] ----------------
__global__ __launch_bounds__(256) void xt_kernel(
    const float* __restrict__ x, u16* __restrict__ xT)
{
  const int b = blockIdx.z, c0 = blockIdx.y * 64, n0 = blockIdx.x * 64;
  __shared__ __align__(16) float T[64][68];
  const int t = threadIdx.x;
  {
    const int cr = t >> 4, nc = (t & 15) * 4;
    #pragma unroll
    for (int ci = 0; ci < 4; ++ci) {
      const float4 v = *(const float4*)&x[((size_t)(b * CDIM + c0 + cr + ci * 16)) * NDIM + n0 + nc];
      *(float4*)&T[cr + ci * 16][nc] = v;
    }
  }
  __syncthreads();
  {
    const int n = t >> 2, g = t & 3;
    union { u16 u[16]; uint4 v[2]; } pk;
    #pragma unroll
    for (int u_ = 0; u_ < 16; ++u_) pk.u[u_] = f2bf(T[g * 16 + u_][n]);
    uint4* dst = (uint4*)&xT[((size_t)(b * NDIM + n0 + n)) * CDIM + c0 + g * 16];
    dst[0] = pk.v[0]; dst[1] = pk.v[1];
  }
}

// ---------------- fused Q/K/V projection: full-tile staging, ONE barrier ----------------
// Grid (NDIM/64, 6, BDIM): p = y>>1, o0 = (y&1)*128.
__global__ __launch_bounds__(256, 4) void qkv_kernel(
    const u16* __restrict__ xT, const u16* __restrict__ wb,
    const float* __restrict__ bq, const float* __restrict__ bk,
    const float* __restrict__ bv,
    u16* __restrict__ qT, u16* __restrict__ kT, u16* __restrict__ vB)
{
  const int b = blockIdx.z;
  const int p = blockIdx.y >> 1;
  const int o0 = (blockIdx.y & 1) * 128;
  const int n0 = blockIdx.x * 64;
  const float* bsel = (p == 0) ? bq : (p == 1) ? bk : bv;
  const float wscale = (p == 0) ? QSCALE : 1.0f;

  __shared__ __align__(16) u16 XTs[64][264];   // 528B rows: 16B-aligned
  const int t = threadIdx.x, lane = t & 63, w = t >> 6;
  const int qd = lane >> 4, lm = lane & 15;
  const int sr = t >> 2, sg = (t & 3) * 8;

  // stage the whole 64x256 X tile once (8 coalesced uint4 loads/thread)
  {
    const u16* xsrc = xT + ((size_t)(b * NDIM + n0 + sr)) * CDIM + sg;
    #pragma unroll
    for (int cs = 0; cs < 8; ++cs)
      *(uint4*)&XTs[sr][cs * 32 + sg] = *(const uint4*)(xsrc + cs * 32);
  }
  __syncthreads();

  const u16* wrow0 = wb + (size_t)p * WSZ + (size_t)(o0 + 32 * w + lm) * CDIM + qd * 8;
  const u16* wrow1 = wrow0 + (size_t)16 * CDIM;

  f32x4 acc[4][2];
  #pragma unroll
  for (int nt = 0; nt < 4; ++nt)
    #pragma unroll
    for (int j = 0; j < 2; ++j) acc[nt][j] = (f32x4){0.f, 0.f, 0.f, 0.f};

  #pragma unroll
  for (int cs = 0; cs < 8; ++cs) {
    const bf16x8 wf0 = *(const bf16x8*)(wrow0 + cs * 32);
    const bf16x8 wf1 = *(const bf16x8*)(wrow1 + cs * 32);
    bf16x8 xf[4];
    #pragma unroll
    for (int nt = 0; nt < 4; ++nt)
      xf[nt] = *(const bf16x8*)&XTs[16 * nt + lm][cs * 32 + qd * 8];
    #pragma unroll
    for (int nt = 0; nt < 4; ++nt) {
      if (p < 2) {
        acc[nt][0] = __builtin_amdgcn_mfma_f32_16x16x32_bf16(xf[nt], wf0, acc[nt][0], 0, 0, 0);
        acc[nt][1] = __builtin_amdgcn_mfma_f32_16x16x32_bf16(xf[nt], wf1, acc[nt][1], 0, 0, 0);
      } else {
        acc[nt][0] = __builtin_amdgcn_mfma_f32_16x16x32_bf16(wf0, xf[nt], acc[nt][0], 0, 0, 0);
        acc[nt][1] = __builtin_amdgcn_mfma_f32_16x16x32_bf16(wf1, xf[nt], acc[nt][1], 0, 0, 0);
      }
    }
  }

  if (p < 2) {
    // D[m=n][col=o]: n = n0+16nt+4qd+r, o = o0+32w+16j+lm
    u16* out = (p == 0) ? qT : kT;
    #pragma unroll
    for (int j = 0; j < 2; ++j) {
      const int og = o0 + 32 * w + 16 * j + lm;
      const float bv2 = bsel[og] * wscale;
      #pragma unroll
      for (int nt = 0; nt < 4; ++nt)
        #pragma unroll
        for (int r = 0; r < 4; ++r) {
          const int n = n0 + 16 * nt + 4 * qd + r;
          out[((size_t)(b * NDIM + n)) * CDIM + og] = f2bf(acc[nt][j][r] + bv2);
        }
    }
  } else {
    // D[m=o][col=n]: o = o0+32w+16j+4qd+r, n = n0+16nt+lm
    #pragma unroll
    for (int j = 0; j < 2; ++j) {
      const float4 b4 = *(const float4*)&bsel[o0 + 32 * w + 16 * j + 4 * qd];
      const float bvr[4] = {b4.x, b4.y, b4.z, b4.w};
      #pragma unroll
      for (int nt = 0; nt < 4; ++nt)
        #pragma unroll
        for (int r = 0; r < 4; ++r) {
          const int og = o0 + 32 * w + 16 * j + 4 * qd + r;
          const int n = n0 + 16 * nt + lm;
          vB[((size_t)(b * CDIM + og)) * NDIM + n] = f2bf(acc[nt][j][r] + bvr[r]);
        }
    }
  }
}

// ---------------- K-split(2) flash attention: 1024 threads, 16 waves, 512 q-rows ----------------
// Per-wave structure identical to R22. Grid (NDIM/512, 16, NSPLIT) = 256 blocks
// = 1/CU x 16 waves. Staging: waves 0-7 stage K rows 8w..+8, waves 8-15 stage
// V rows 8(w-8)..+8 (one gload16 per wave).
__global__ __launch_bounds__(1024, 2) void attn_kernel(
    const u16* __restrict__ qT, const u16* __restrict__ kT,
    const u16* __restrict__ vB, u16* __restrict__ Opart,
    float* __restrict__ Lp)
{
  const int bh = blockIdx.y, b = bh >> 2, h = bh & 3;
  const int n0 = blockIdx.x * 512;
  const int z  = blockIdx.z;

  // [buf][0]=K tile, [buf][1]=V tile. 2*2*64*64*2B = 32768 B.
  __shared__ __align__(16) u16 KVlds[2][2][64][64];

  const int t = threadIdx.x, lane = t & 63, w = t >> 6;   // w in 0..15
  const int qd = lane >> 4, lm = lane & 15, l7 = lm & 7;

  // Q fragments straight from global: wave w owns q-rows 16*(2w+s)+lm.
  bf16x8 qf[2][2];
  {
    const u16* qbase = qT + ((size_t)(b * NDIM) + n0) * CDIM + h * 64;
    #pragma unroll
    for (int s = 0; s < 2; ++s)
      #pragma unroll
      for (int hh = 0; hh < 2; ++hh)
        qf[s][hh] = *(const bf16x8*)(qbase +
            (size_t)(16 * (2 * w + s) + lm) * CDIM + 32 * hh + qd * 8);
  }

  // ones A-fragment for the l-sum MFMA (bf16 1.0 = 0x3F80)
  const s16x4 ones = (s16x4){(short)0x3F80, (short)0x3F80, (short)0x3F80, (short)0x3F80};
  f32x4 la[2];
  la[0] = (f32x4){0.f, 0.f, 0.f, 0.f};
  la[1] = (f32x4){0.f, 0.f, 0.f, 0.f};

  f32x4 oa[2][4];
  #pragma unroll
  for (int s = 0; s < 2; ++s)
    #pragma unroll
    for (int dt = 0; dt < 4; ++dt) oa[s][dt] = (f32x4){0.f, 0.f, 0.f, 0.f};

  // staging: sw = w&7 covers tile rows 8*sw..+8; lane -> row 8*sw+(lane>>3),
  // 16B granule (lane&7), source granule pre-swizzled: ^(row&7) = ^(lane>>3).
  const int sw = w & 7;
  const int srow = lane >> 3;
  const int swz  = 8 * ((lane & 7) ^ srow);       // elems
  const u16* kp0 = kT + ((size_t)(b * NDIM + z * KPERZ + 8 * sw + srow)) * CDIM + h * 64 + swz;
  const u16* vp0 = vB + ((size_t)(b * CDIM + h * 64 + 8 * sw + srow)) * NDIM + z * KPERZ + swz;

  // prologue: stage tile 0 into buf 0 (one gload16 per wave)
  if (w < 8) gload16(kp0, &KVlds[0][0][0][0] + sw * 512);
  else       gload16(vp0, &KVlds[0][1][0][0] + sw * 512);

  #pragma unroll 1
  for (int it = 0; it < KPERZ / 64; ++it) {
    __syncthreads();   // vmcnt(0) drain: tile 'it' landed; all waves synced
    if (it + 1 < KPERZ / 64) {
      const size_t ko = (size_t)(it + 1) * 64 * CDIM;
      const int    vo = (it + 1) * 64;
      if (w < 8) gload16(kp0 + ko, &KVlds[(it + 1) & 1][0][0][0] + sw * 512);
      else       gload16(vp0 + vo, &KVlds[(it + 1) & 1][1][0][0] + sw * 512);
    }
    const u16 (*Kt)[64] = KVlds[it & 1][0];
    const u16 (*Vt)[64] = KVlds[it & 1][1];

    // P fragments, packed bf16 at production: pk[s][c].v is the PV B-operand
    union { u16 u[4]; u32 d[2]; s16x4 v; } pk[2][4];

    #pragma unroll
    for (int nt = 0; nt < 4; ++nt) {
      // swizzled read: granule (4hh+qd) ^ (row&7), row&7 == lm&7
      const bf16x8 kf0 = *(const bf16x8*)&Kt[16 * nt + lm][8 * (qd ^ l7)];
      const bf16x8 kf1 = *(const bf16x8*)&Kt[16 * nt + lm][8 * ((4 + qd) ^ l7)];
      #pragma unroll
      for (int s = 0; s < 2; ++s) {
        f32x4 zz = (f32x4){0.f, 0.f, 0.f, 0.f};
        zz = __builtin_amdgcn_mfma_f32_16x16x32_bf16(kf0, qf[s][0], zz, 0, 0, 0);
        zz = __builtin_amdgcn_mfma_f32_16x16x32_bf16(kf1, qf[s][1], zz, 0, 0, 0);
        const float p0 = __builtin_amdgcn_exp2f(zz[0]);
        const float p1 = __builtin_amdgcn_exp2f(zz[1]);
        const float p2 = __builtin_amdgcn_exp2f(zz[2]);
        const float p3 = __builtin_amdgcn_exp2f(zz[3]);
        pk[s][nt].d[0] = pk2(p0, p1);
        pk[s][nt].d[1] = pk2(p2, p3);
      }
    }

    #pragma unroll
    for (int c = 0; c < 4; ++c) {
      s16x4 av[4];
      #pragma unroll
      for (int dt = 0; dt < 4; ++dt)
        av[dt] = *(const s16x4*)&Vt[16 * dt + lm][(16 * c + 4 * qd) ^ (8 * l7)];
      // l-sum on the MFMA pipe: every output row = sum_k P[k][q], col q = lm
      la[0] = __builtin_amdgcn_mfma_f32_16x16x16bf16_1k(ones, pk[0][c].v, la[0], 0, 0, 0);
      la[1] = __builtin_amdgcn_mfma_f32_16x16x16bf16_1k(ones, pk[1][c].v, la[1], 0, 0, 0);
      #pragma unroll
      for (int dt = 0; dt < 4; ++dt) {
        oa[0][dt] = __builtin_amdgcn_mfma_f32_16x16x16bf16_1k(av[dt], pk[0][c].v, oa[0][dt], 0, 0, 0);
        oa[1][dt] = __builtin_amdgcn_mfma_f32_16x16x16bf16_1k(av[dt], pk[1][c].v, oa[1][dt], 0, 0, 0);
      }
    }
  }

  // la[s][r] identical across r and across qd quads: full l for q = lm.
  const float l_i[2] = {la[0][0], la[1][0]};

  if (qd == 0) {
    const size_t lbase = ((size_t)z * (BDIM * HDIM) + bh) * NDIM;
    #pragma unroll
    for (int s = 0; s < 2; ++s)
      Lp[lbase + n0 + 16 * (2 * w + s) + lm] = l_i[s];
  }

  __syncthreads();   // all waves done reading the last tile before overlay
  // epilogue: normalize + transpose via LDS overlay in FOUR phases of 128 rows.
  u16 (*Ot)[72] = (u16(*)[72])&KVlds[0][0][0][0];   // [128][72] = 18432B fits
  #pragma unroll
  for (int ph = 0; ph < 4; ++ph) {
    if ((w >> 2) == ph) {
      const int wl = w & 3;
      #pragma unroll
      for (int s = 0; s < 2; ++s) {
        const float inv = 1.0f / l_i[s];
        #pragma unroll
        for (int dt = 0; dt < 4; ++dt)
          #pragma unroll
          for (int r = 0; r < 4; ++r)
            Ot[16 * (2 * wl + s) + lm][16 * dt + 4 * qd + r] = f2bf(oa[s][dt][r] * inv);
      }
    }
    __syncthreads();
    {
      const int r = t >> 3, g = (t & 7) * 8;   // 1024 thr x 16B = 128 rows x 128B
      u16* dst = Opart + (((size_t)z * (BDIM * HDIM) + bh) * NDIM + n0 + ph * 128 + r) * DKDIM + g;
      *(uint4*)dst = *(const uint4*)&Ot[r][g];
    }
    __syncthreads();
  }
}

// ---------------- output projection, W direct-from-global bf16, 2-way combine ----------------
// Grid (NDIM/64, 2, BDIM). Combine weights = l ratios (shift-free partials).
__global__ __launch_bounds__(256, 4) void projout_kernel(
    const u16* __restrict__ Opart, const float* __restrict__ Lp,
    const u16* __restrict__ wb, const float* __restrict__ bp,
    const float* __restrict__ res, float* __restrict__ out)
{
  const int b = blockIdx.z, o0 = blockIdx.y * 128, n0 = blockIdx.x * 64;
  __shared__ __align__(16) u16 XTs[64][40];
  const int t = threadIdx.x, lane = t & 63, w = t >> 6;
  const int qd = lane >> 4, lm = lane & 15;
  const int sr = t >> 2, sg = (t & 3) * 8;

  float wh[4][NSPLIT];
  #pragma unroll
  for (int hh = 0; hh < 4; ++hh) {
    const size_t i0 = ((size_t)(b * HDIM + hh)) * NDIM + n0 + sr;
    float l[NSPLIT], tot = 0.f;
    #pragma unroll
    for (int zz = 0; zz < NSPLIT; ++zz) { l[zz] = Lp[(size_t)zz * NQ + i0]; tot += l[zz]; }
    const float iv = 1.0f / tot;
    #pragma unroll
    for (int zz = 0; zz < NSPLIT; ++zz) wh[hh][zz] = l[zz] * iv;
  }

  const u16* wrow0 = wb + (size_t)3 * WSZ + (size_t)(o0 + 32 * w + lm) * CDIM + qd * 8;
  const u16* wrow1 = wrow0 + (size_t)16 * CDIM;

  f32x4 acc[4][2];
  #pragma unroll
  for (int nt = 0; nt < 4; ++nt)
    #pragma unroll
    for (int j = 0; j < 2; ++j) acc[nt][j] = (f32x4){0.f, 0.f, 0.f, 0.f};

  for (int cs = 0; cs < 8; ++cs) {
    const int c0 = cs * 32;
    const int hh = c0 >> 6;
    const int dk = (c0 & 63) + sg;
    const bf16x8 wf0 = *(const bf16x8*)(wrow0 + c0);
    const bf16x8 wf1 = *(const bf16x8*)(wrow1 + c0);
    __syncthreads();
    {
      const size_t obase = (((size_t)(b * HDIM + hh)) * NDIM + n0 + sr) * DKDIM + dk;
      float v[8] = {0.f, 0.f, 0.f, 0.f, 0.f, 0.f, 0.f, 0.f};
      #pragma unroll
      for (int zz = 0; zz < NSPLIT; ++zz) {
        union { u16 u[8]; uint4 q; } a;
        a.q = *(const uint4*)(Opart + (size_t)zz * NQ * DKDIM + obase);
        const float wz = wh[hh][zz];
        #pragma unroll
        for (int j = 0; j < 8; ++j) v[j] = fmaf(wz, bf2f(a.u[j]), v[j]);
      }
      union { u16 u[8]; uint4 q; } ov;
      #pragma unroll
      for (int j = 0; j < 8; ++j) ov.u[j] = f2bf(v[j]);
      *(uint4*)&XTs[sr][sg] = ov.q;
    }
    __syncthreads();
    bf16x8 xf[4];
    #pragma unroll
    for (int nt = 0; nt < 4; ++nt) xf[nt] = *(const bf16x8*)&XTs[16 * nt + lm][qd * 8];
    #pragma unroll
    for (int nt = 0; nt < 4; ++nt) {
      acc[nt][0] = __builtin_amdgcn_mfma_f32_16x16x32_bf16(wf0, xf[nt], acc[nt][0], 0, 0, 0);
      acc[nt][1] = __builtin_amdgcn_mfma_f32_16x16x32_bf16(wf1, xf[nt], acc[nt][1], 0, 0, 0);
    }
  }

  // D[m=o][col=n]: o = o0+32w+16j+4qd+r, n = n0+16nt+lm
  #pragma unroll
  for (int j = 0; j < 2; ++j) {
    const float4 b4 = *(const float4*)&bp[o0 + 32 * w + 16 * j + 4 * qd];
    const float bvr[4] = {b4.x, b4.y, b4.z, b4.w};
    #pragma unroll
    for (int nt = 0; nt < 4; ++nt)
      #pragma unroll
      for (int r = 0; r < 4; ++r) {
        const int og = o0 + 32 * w + 16 * j + 4 * qd + r;
        const int n = n0 + 16 * nt + lm;
        const size_t idx = ((size_t)(b * CDIM + og)) * NDIM + n;
        out[idx] = acc[nt][j][r] + bvr[r] + res[idx];
      }
  }
}

extern "C" void kernel_launch(void* const* d_in, const int* in_sizes, int n_in,
                              void* d_out, int out_size, void* d_ws, size_t ws_size,
                              hipStream_t stream)
{
  const float* x  = (const float*)d_in[0];
  const float* wq = (const float*)d_in[1];
  const float* bq = (const float*)d_in[2];
  const float* wk = (const float*)d_in[3];
  const float* bk = (const float*)d_in[4];
  const float* wv = (const float*)d_in[5];
  const float* bv = (const float*)d_in[6];
  const float* wp = (const float*)d_in[7];
  const float* bp = (const float*)d_in[8];
  float* out = (float*)d_out;

  const size_t sz = (size_t)BDIM * CDIM * NDIM;   // 4.19M elements
  u16* xTb = (u16*)d_ws;
  u16* qTb = xTb + sz;
  u16* kTb = qTb + sz;
  u16* vBb = kTb + sz;
  u16* Opart = vBb + sz;                          // NSPLIT*sz u16
  float* Lp = (float*)(Opart + (size_t)NSPLIT * sz);  // NSPLIT*NQ floats
  u16* wbf = (u16*)(Lp + (size_t)NSPLIT * NQ);    // 4*WSZ u16 (512KB)

  const dim3 blk(256);
  wconv_kernel<<<dim3(WSZ / (256 * 8), 4, 1), blk, 0, stream>>>(wq, wk, wv, wp, wbf);
  xt_kernel<<<dim3(NDIM / 64, CDIM / 64, BDIM), blk, 0, stream>>>(x, xTb);
  qkv_kernel<<<dim3(NDIM / 64, 6, BDIM), blk, 0, stream>>>(
      xTb, wbf, bq, bk, bv, qTb, kTb, vBb);
  attn_kernel<<<dim3(NDIM / 512, BDIM * HDIM, NSPLIT), dim3(1024), 0, stream>>>(
      qTb, kTb, vBb, Opart, Lp);
  projout_kernel<<<dim3(NDIM / 64, 2, BDIM), blk, 0, stream>>>(
      Opart, Lp, wbf, bp, x, out);
}

// Round 15
// 195.476 us; speedup vs baseline: 1.0038x; 1.0038x over previous
//
#include <hip/hip_runtime.h>

// Attention_72902774882333 — R24: hybrid K/V staging in attn. Conflicts pinned
// at 8.585M since R14 (~15% of attn cycles): bank math shows XOR'd V b64 reads
// lose the row-term bank spread (128B rows -> bank = e/2 only), while the R12
// padded [64][72] V layout is conflict-free on both write (4(r8+l8)) and read
// (4*lm row spread). R24: K stays gload_lds+XOR (proven conflict-free); V is
// reg-staged (load at loop top, ds_write_b128 at loop end) into padded [64][72]
// double buffer. Single-barrier loop preserved. attn only; rest = R23.
// B=4, C=256, N=4096, H=4, DK=64.

#define BDIM 4
#define CDIM 256
#define NDIM 4096
#define HDIM 4
#define DKDIM 64
#define NQ   (BDIM * HDIM * NDIM)       // 65536
#define NSPLIT 2
#define KPERZ (NDIM / NSPLIT)           // 2048 keys per split
#define QSCALE 0.18033688011112042f     // log2(e)/8
#define WSZ (CDIM * CDIM)               // 65536 elems per weight matrix

typedef __bf16 bf16x8 __attribute__((ext_vector_type(8)));
typedef float f32x4 __attribute__((ext_vector_type(4)));
typedef short s16x4 __attribute__((ext_vector_type(4)));
typedef unsigned short u16;
typedef unsigned int u32;

__device__ __forceinline__ u16 f2bf(float f) {
  union { __bf16 h; u16 s; } u; u.h = (__bf16)f; return u.s;
}
__device__ __forceinline__ float bf2f(u16 v) {
  union { u32 u; float f; } x; x.u = (u32)v << 16; return x.f;
}
__device__ __forceinline__ u32 pk2(float a, float b) {
  return (u32)f2bf(a) | ((u32)f2bf(b) << 16);
}
__device__ __forceinline__ void gload16(const u16* g, u16* l) {
  __builtin_amdgcn_global_load_lds(
      (const __attribute__((address_space(1))) void*)g,
      (__attribute__((address_space(3))) void*)l, 16, 0, 0);
}

// ---------------- weight conversion: fp32 -> bf16, once ----------------
// wb layout: [4][WSZ] = wq(scaled), wk, wv, wp. Grid (32, 4).
__global__ __launch_bounds__(256) void wconv_kernel(
    const float* __restrict__ wq, const float* __restrict__ wk,
    const float* __restrict__ wv, const float* __restrict__ wp,
    u16* __restrict__ wb)
{
  const int a = blockIdx.y;
  const float* src = (a == 0) ? wq : (a == 1) ? wk : (a == 2) ? wv : wp;
  const float sc = (a == 0) ? QSCALE : 1.0f;
  const int i = (blockIdx.x * 256 + threadIdx.x) * 8;
  const float4 v0 = *(const float4*)(src + i);
  const float4 v1 = *(const float4*)(src + i + 4);
  union { u32 p[4]; uint4 q; } o;
  o.p[0] = pk2(v0.x * sc, v0.y * sc);
  o.p[1] = pk2(v0.z * sc, v0.w * sc);
  o.p[2] = pk2(v1.x * sc, v1.y * sc);
  o.p[3] = pk2(v1.z * sc, v1.w * sc);
  *(uint4*)(wb + (size_t)a * WSZ + i) = o.q;
}

// ---------------- x transpose: fp32 [b][c][n] -> bf16 [b][n][256] ----------------
__global__ __launch_bounds__(256) void xt_kernel(
    const float* __restrict__ x, u16* __restrict__ xT)
{
  const int b = blockIdx.z, c0 = blockIdx.y * 64, n0 = blockIdx.x * 64;
  __shared__ __align__(16) float T[64][68];
  const int t = threadIdx.x;
  {
    const int cr = t >> 4, nc = (t & 15) * 4;
    #pragma unroll
    for (int ci = 0; ci < 4; ++ci) {
      const float4 v = *(const float4*)&x[((size_t)(b * CDIM + c0 + cr + ci * 16)) * NDIM + n0 + nc];
      *(float4*)&T[cr + ci * 16][nc] = v;
    }
  }
  __syncthreads();
  {
    const int n = t >> 2, g = t & 3;
    union { u16 u[16]; uint4 v[2]; } pk;
    #pragma unroll
    for (int u_ = 0; u_ < 16; ++u_) pk.u[u_] = f2bf(T[g * 16 + u_][n]);
    uint4* dst = (uint4*)&xT[((size_t)(b * NDIM + n0 + n)) * CDIM + c0 + g * 16];
    dst[0] = pk.v[0]; dst[1] = pk.v[1];
  }
}

// ---------------- fused Q/K/V projection: full-tile staging, ONE barrier ----------------
// Grid (NDIM/64, 6, BDIM): p = y>>1, o0 = (y&1)*128.
__global__ __launch_bounds__(256, 4) void qkv_kernel(
    const u16* __restrict__ xT, const u16* __restrict__ wb,
    const float* __restrict__ bq, const float* __restrict__ bk,
    const float* __restrict__ bv,
    u16* __restrict__ qT, u16* __restrict__ kT, u16* __restrict__ vB)
{
  const int b = blockIdx.z;
  const int p = blockIdx.y >> 1;
  const int o0 = (blockIdx.y & 1) * 128;
  const int n0 = blockIdx.x * 64;
  const float* bsel = (p == 0) ? bq : (p == 1) ? bk : bv;
  const float wscale = (p == 0) ? QSCALE : 1.0f;

  __shared__ __align__(16) u16 XTs[64][264];   // 528B rows: 16B-aligned
  const int t = threadIdx.x, lane = t & 63, w = t >> 6;
  const int qd = lane >> 4, lm = lane & 15;
  const int sr = t >> 2, sg = (t & 3) * 8;

  // stage the whole 64x256 X tile once (8 coalesced uint4 loads/thread)
  {
    const u16* xsrc = xT + ((size_t)(b * NDIM + n0 + sr)) * CDIM + sg;
    #pragma unroll
    for (int cs = 0; cs < 8; ++cs)
      *(uint4*)&XTs[sr][cs * 32 + sg] = *(const uint4*)(xsrc + cs * 32);
  }
  __syncthreads();

  const u16* wrow0 = wb + (size_t)p * WSZ + (size_t)(o0 + 32 * w + lm) * CDIM + qd * 8;
  const u16* wrow1 = wrow0 + (size_t)16 * CDIM;

  f32x4 acc[4][2];
  #pragma unroll
  for (int nt = 0; nt < 4; ++nt)
    #pragma unroll
    for (int j = 0; j < 2; ++j) acc[nt][j] = (f32x4){0.f, 0.f, 0.f, 0.f};

  #pragma unroll
  for (int cs = 0; cs < 8; ++cs) {
    const bf16x8 wf0 = *(const bf16x8*)(wrow0 + cs * 32);
    const bf16x8 wf1 = *(const bf16x8*)(wrow1 + cs * 32);
    bf16x8 xf[4];
    #pragma unroll
    for (int nt = 0; nt < 4; ++nt)
      xf[nt] = *(const bf16x8*)&XTs[16 * nt + lm][cs * 32 + qd * 8];
    #pragma unroll
    for (int nt = 0; nt < 4; ++nt) {
      if (p < 2) {
        acc[nt][0] = __builtin_amdgcn_mfma_f32_16x16x32_bf16(xf[nt], wf0, acc[nt][0], 0, 0, 0);
        acc[nt][1] = __builtin_amdgcn_mfma_f32_16x16x32_bf16(xf[nt], wf1, acc[nt][1], 0, 0, 0);
      } else {
        acc[nt][0] = __builtin_amdgcn_mfma_f32_16x16x32_bf16(wf0, xf[nt], acc[nt][0], 0, 0, 0);
        acc[nt][1] = __builtin_amdgcn_mfma_f32_16x16x32_bf16(wf1, xf[nt], acc[nt][1], 0, 0, 0);
      }
    }
  }

  if (p < 2) {
    // D[m=n][col=o]: n = n0+16nt+4qd+r, o = o0+32w+16j+lm
    u16* out = (p == 0) ? qT : kT;
    #pragma unroll
    for (int j = 0; j < 2; ++j) {
      const int og = o0 + 32 * w + 16 * j + lm;
      const float bv2 = bsel[og] * wscale;
      #pragma unroll
      for (int nt = 0; nt < 4; ++nt)
        #pragma unroll
        for (int r = 0; r < 4; ++r) {
          const int n = n0 + 16 * nt + 4 * qd + r;
          out[((size_t)(b * NDIM + n)) * CDIM + og] = f2bf(acc[nt][j][r] + bv2);
        }
    }
  } else {
    // D[m=o][col=n]: o = o0+32w+16j+4qd+r, n = n0+16nt+lm
    #pragma unroll
    for (int j = 0; j < 2; ++j) {
      const float4 b4 = *(const float4*)&bsel[o0 + 32 * w + 16 * j + 4 * qd];
      const float bvr[4] = {b4.x, b4.y, b4.z, b4.w};
      #pragma unroll
      for (int nt = 0; nt < 4; ++nt)
        #pragma unroll
        for (int r = 0; r < 4; ++r) {
          const int og = o0 + 32 * w + 16 * j + 4 * qd + r;
          const int n = n0 + 16 * nt + lm;
          vB[((size_t)(b * CDIM + og)) * NDIM + n] = f2bf(acc[nt][j][r] + bvr[r]);
        }
    }
  }
}

// ---------------- K-split(2) flash attention: 16 waves, hybrid K/V staging ----------------
// K: gload_lds + XOR-16B-granule swizzle (conflict-free b128 reads).
// V: register-staged into padded [64][72] (conflict-free b64 reads + writes).
// Grid (NDIM/512, 16, NSPLIT) = 256 blocks = 1/CU x 16 waves.
__global__ __launch_bounds__(1024, 2) void attn_kernel(
    const u16* __restrict__ qT, const u16* __restrict__ kT,
    const u16* __restrict__ vB, u16* __restrict__ Opart,
    float* __restrict__ Lp)
{
  const int bh = blockIdx.y, b = bh >> 2, h = bh & 3;
  const int n0 = blockIdx.x * 512;
  const int z  = blockIdx.z;

  // contiguous LDS: K [2][64][64] (16KB) + V [2][64][72] (18.4KB) = 34.8KB
  struct SH { u16 K[2][64][64]; u16 V[2][64][72]; };
  __shared__ __align__(16) SH sh;

  const int t = threadIdx.x, lane = t & 63, w = t >> 6;   // w in 0..15
  const int qd = lane >> 4, lm = lane & 15, l7 = lm & 7;

  // Q fragments straight from global: wave w owns q-rows 16*(2w+s)+lm.
  bf16x8 qf[2][2];
  {
    const u16* qbase = qT + ((size_t)(b * NDIM) + n0) * CDIM + h * 64;
    #pragma unroll
    for (int s = 0; s < 2; ++s)
      #pragma unroll
      for (int hh = 0; hh < 2; ++hh)
        qf[s][hh] = *(const bf16x8*)(qbase +
            (size_t)(16 * (2 * w + s) + lm) * CDIM + 32 * hh + qd * 8);
  }

  // ones A-fragment for the l-sum MFMA (bf16 1.0 = 0x3F80)
  const s16x4 ones = (s16x4){(short)0x3F80, (short)0x3F80, (short)0x3F80, (short)0x3F80};
  f32x4 la[2];
  la[0] = (f32x4){0.f, 0.f, 0.f, 0.f};
  la[1] = (f32x4){0.f, 0.f, 0.f, 0.f};

  f32x4 oa[2][4];
  #pragma unroll
  for (int s = 0; s < 2; ++s)
    #pragma unroll
    for (int dt = 0; dt < 4; ++dt) oa[s][dt] = (f32x4){0.f, 0.f, 0.f, 0.f};

  // staging geometry: sw = w&7 covers tile rows 8*sw..+8; lane -> row 8*sw+r8.
  const int sw = w & 7;
  const int r8 = lane >> 3, l8 = lane & 7;
  // K source: 16B granule pre-swizzled ^(row&7) = ^r8 (paired with XOR'd read)
  const int kswz = 8 * (l8 ^ r8);
  const u16* kp0 = kT + ((size_t)(b * NDIM + z * KPERZ + 8 * sw + r8)) * CDIM + h * 64 + kswz;
  // V source: plain (no swizzle) — dest is padded, written via ds_write
  const u16* vp0 = vB + ((size_t)(b * CDIM + h * 64 + 8 * sw + r8)) * NDIM + z * KPERZ + 8 * l8;

  // prologue: stage tile 0 into buf 0
  if (w < 8) {
    gload16(kp0, &sh.K[0][0][0] + sw * 512);
  } else {
    const uint4 v0 = *(const uint4*)(vp0);
    *(uint4*)&sh.V[0][8 * sw + r8][8 * l8] = v0;
  }

  uint4 vreg;
  #pragma unroll 1
  for (int it = 0; it < KPERZ / 64; ++it) {
    __syncthreads();   // vmcnt(0) drain: tile 'it' K landed; V writes visible
    const bool pf = (it + 1 < KPERZ / 64);
    if (pf) {
      if (w < 8) {
        gload16(kp0 + (size_t)(it + 1) * 64 * CDIM,
                &sh.K[(it + 1) & 1][0][0] + sw * 512);
      } else {
        vreg = *(const uint4*)(vp0 + (it + 1) * 64);   // latency hides under compute
      }
    }
    const u16 (*Kt)[64] = sh.K[it & 1];
    const u16 (*Vt)[72] = sh.V[it & 1];

    // P fragments, packed bf16 at production: pk[s][c].v is the PV B-operand
    union { u16 u[4]; u32 d[2]; s16x4 v; } pk[2][4];

    #pragma unroll
    for (int nt = 0; nt < 4; ++nt) {
      // swizzled read: granule (4hh+qd) ^ (row&7), row&7 == lm&7
      const bf16x8 kf0 = *(const bf16x8*)&Kt[16 * nt + lm][8 * (qd ^ l7)];
      const bf16x8 kf1 = *(const bf16x8*)&Kt[16 * nt + lm][8 * ((4 + qd) ^ l7)];
      #pragma unroll
      for (int s = 0; s < 2; ++s) {
        f32x4 zz = (f32x4){0.f, 0.f, 0.f, 0.f};
        zz = __builtin_amdgcn_mfma_f32_16x16x32_bf16(kf0, qf[s][0], zz, 0, 0, 0);
        zz = __builtin_amdgcn_mfma_f32_16x16x32_bf16(kf1, qf[s][1], zz, 0, 0, 0);
        const float p0 = __builtin_amdgcn_exp2f(zz[0]);
        const float p1 = __builtin_amdgcn_exp2f(zz[1]);
        const float p2 = __builtin_amdgcn_exp2f(zz[2]);
        const float p3 = __builtin_amdgcn_exp2f(zz[3]);
        pk[s][nt].d[0] = pk2(p0, p1);
        pk[s][nt].d[1] = pk2(p2, p3);
      }
    }

    #pragma unroll
    for (int c = 0; c < 4; ++c) {
      s16x4 av[4];
      #pragma unroll
      for (int dt = 0; dt < 4; ++dt)
        av[dt] = *(const s16x4*)&Vt[16 * dt + lm][16 * c + 4 * qd];   // padded: no XOR
      // l-sum on the MFMA pipe: every output row = sum_k P[k][q], col q = lm
      la[0] = __builtin_amdgcn_mfma_f32_16x16x16bf16_1k(ones, pk[0][c].v, la[0], 0, 0, 0);
      la[1] = __builtin_amdgcn_mfma_f32_16x16x16bf16_1k(ones, pk[1][c].v, la[1], 0, 0, 0);
      #pragma unroll
      for (int dt = 0; dt < 4; ++dt) {
        oa[0][dt] = __builtin_amdgcn_mfma_f32_16x16x16bf16_1k(av[dt], pk[0][c].v, oa[0][dt], 0, 0, 0);
        oa[1][dt] = __builtin_amdgcn_mfma_f32_16x16x16bf16_1k(av[dt], pk[1][c].v, oa[1][dt], 0, 0, 0);
      }
    }

    // write prefetched V into the other buffer (safe: buf (it+1)&1 was last
    // read in iteration it-1, and ALL waves passed the barrier at top of it)
    if (pf && w >= 8)
      *(uint4*)&sh.V[(it + 1) & 1][8 * sw + r8][8 * l8] = vreg;
  }

  // la[s][r] identical across r and across qd quads: full l for q = lm.
  const float l_i[2] = {la[0][0], la[1][0]};

  if (qd == 0) {
    const size_t lbase = ((size_t)z * (BDIM * HDIM) + bh) * NDIM;
    #pragma unroll
    for (int s = 0; s < 2; ++s)
      Lp[lbase + n0 + 16 * (2 * w + s) + lm] = l_i[s];
  }

  __syncthreads();   // all waves done reading the last tile before overlay
  // epilogue: normalize + transpose via LDS overlay in FOUR phases of 128 rows.
  u16 (*Ot)[72] = (u16(*)[72])&sh.K[0][0][0];   // [128][72] = 18.4KB fits in 34.8KB
  #pragma unroll
  for (int ph = 0; ph < 4; ++ph) {
    if ((w >> 2) == ph) {
      const int wl = w & 3;
      #pragma unroll
      for (int s = 0; s < 2; ++s) {
        const float inv = 1.0f / l_i[s];
        #pragma unroll
        for (int dt = 0; dt < 4; ++dt)
          #pragma unroll
          for (int r = 0; r < 4; ++r)
            Ot[16 * (2 * wl + s) + lm][16 * dt + 4 * qd + r] = f2bf(oa[s][dt][r] * inv);
      }
    }
    __syncthreads();
    {
      const int r = t >> 3, g = (t & 7) * 8;   // 1024 thr x 16B = 128 rows x 128B
      u16* dst = Opart + (((size_t)z * (BDIM * HDIM) + bh) * NDIM + n0 + ph * 128 + r) * DKDIM + g;
      *(uint4*)dst = *(const uint4*)&Ot[r][g];
    }
    __syncthreads();
  }
}

// ---------------- output projection, W direct-from-global bf16, 2-way combine ----------------
// Grid (NDIM/64, 2, BDIM). Combine weights = l ratios (shift-free partials).
__global__ __launch_bounds__(256, 4) void projout_kernel(
    const u16* __restrict__ Opart, const float* __restrict__ Lp,
    const u16* __restrict__ wb, const float* __restrict__ bp,
    const float* __restrict__ res, float* __restrict__ out)
{
  const int b = blockIdx.z, o0 = blockIdx.y * 128, n0 = blockIdx.x * 64;
  __shared__ __align__(16) u16 XTs[64][40];
  const int t = threadIdx.x, lane = t & 63, w = t >> 6;
  const int qd = lane >> 4, lm = lane & 15;
  const int sr = t >> 2, sg = (t & 3) * 8;

  float wh[4][NSPLIT];
  #pragma unroll
  for (int hh = 0; hh < 4; ++hh) {
    const size_t i0 = ((size_t)(b * HDIM + hh)) * NDIM + n0 + sr;
    float l[NSPLIT], tot = 0.f;
    #pragma unroll
    for (int zz = 0; zz < NSPLIT; ++zz) { l[zz] = Lp[(size_t)zz * NQ + i0]; tot += l[zz]; }
    const float iv = 1.0f / tot;
    #pragma unroll
    for (int zz = 0; zz < NSPLIT; ++zz) wh[hh][zz] = l[zz] * iv;
  }

  const u16* wrow0 = wb + (size_t)3 * WSZ + (size_t)(o0 + 32 * w + lm) * CDIM + qd * 8;
  const u16* wrow1 = wrow0 + (size_t)16 * CDIM;

  f32x4 acc[4][2];
  #pragma unroll
  for (int nt = 0; nt < 4; ++nt)
    #pragma unroll
    for (int j = 0; j < 2; ++j) acc[nt][j] = (f32x4){0.f, 0.f, 0.f, 0.f};

  for (int cs = 0; cs < 8; ++cs) {
    const int c0 = cs * 32;
    const int hh = c0 >> 6;
    const int dk = (c0 & 63) + sg;
    const bf16x8 wf0 = *(const bf16x8*)(wrow0 + c0);
    const bf16x8 wf1 = *(const bf16x8*)(wrow1 + c0);
    __syncthreads();
    {
      const size_t obase = (((size_t)(b * HDIM + hh)) * NDIM + n0 + sr) * DKDIM + dk;
      float v[8] = {0.f, 0.f, 0.f, 0.f, 0.f, 0.f, 0.f, 0.f};
      #pragma unroll
      for (int zz = 0; zz < NSPLIT; ++zz) {
        union { u16 u[8]; uint4 q; } a;
        a.q = *(const uint4*)(Opart + (size_t)zz * NQ * DKDIM + obase);
        const float wz = wh[hh][zz];
        #pragma unroll
        for (int j = 0; j < 8; ++j) v[j] = fmaf(wz, bf2f(a.u[j]), v[j]);
      }
      union { u16 u[8]; uint4 q; } ov;
      #pragma unroll
      for (int j = 0; j < 8; ++j) ov.u[j] = f2bf(v[j]);
      *(uint4*)&XTs[sr][sg] = ov.q;
    }
    __syncthreads();
    bf16x8 xf[4];
    #pragma unroll
    for (int nt = 0; nt < 4; ++nt) xf[nt] = *(const bf16x8*)&XTs[16 * nt + lm][qd * 8];
    #pragma unroll
    for (int nt = 0; nt < 4; ++nt) {
      acc[nt][0] = __builtin_amdgcn_mfma_f32_16x16x32_bf16(wf0, xf[nt], acc[nt][0], 0, 0, 0);
      acc[nt][1] = __builtin_amdgcn_mfma_f32_16x16x32_bf16(wf1, xf[nt], acc[nt][1], 0, 0, 0);
    }
  }

  // D[m=o][col=n]: o = o0+32w+16j+4qd+r, n = n0+16nt+lm
  #pragma unroll
  for (int j = 0; j < 2; ++j) {
    const float4 b4 = *(const float4*)&bp[o0 + 32 * w + 16 * j + 4 * qd];
    const float bvr[4] = {b4.x, b4.y, b4.z, b4.w};
    #pragma unroll
    for (int nt = 0; nt < 4; ++nt)
      #pragma unroll
      for (int r = 0; r < 4; ++r) {
        const int og = o0 + 32 * w + 16 * j + 4 * qd + r;
        const int n = n0 + 16 * nt + lm;
        const size_t idx = ((size_t)(b * CDIM + og)) * NDIM + n;
        out[idx] = acc[nt][j][r] + bvr[r] + res[idx];
      }
  }
}

extern "C" void kernel_launch(void* const* d_in, const int* in_sizes, int n_in,
                              void* d_out, int out_size, void* d_ws, size_t ws_size,
                              hipStream_t stream)
{
  const float* x  = (const float*)d_in[0];
  const float* wq = (const float*)d_in[1];
  const float* bq = (const float*)d_in[2];
  const float* wk = (const float*)d_in[3];
  const float* bk = (const float*)d_in[4];
  const float* wv = (const float*)d_in[5];
  const float* bv = (const float*)d_in[6];
  const float* wp = (const float*)d_in[7];
  const float* bp = (const float*)d_in[8];
  float* out = (float*)d_out;

  const size_t sz = (size_t)BDIM * CDIM * NDIM;   // 4.19M elements
  u16* xTb = (u16*)d_ws;
  u16* qTb = xTb + sz;
  u16* kTb = qTb + sz;
  u16* vBb = kTb + sz;
  u16* Opart = vBb + sz;                          // NSPLIT*sz u16
  float* Lp = (float*)(Opart + (size_t)NSPLIT * sz);  // NSPLIT*NQ floats
  u16* wbf = (u16*)(Lp + (size_t)NSPLIT * NQ);    // 4*WSZ u16 (512KB)

  const dim3 blk(256);
  wconv_kernel<<<dim3(WSZ / (256 * 8), 4, 1), blk, 0, stream>>>(wq, wk, wv, wp, wbf);
  xt_kernel<<<dim3(NDIM / 64, CDIM / 64, BDIM), blk, 0, stream>>>(x, xTb);
  qkv_kernel<<<dim3(NDIM / 64, 6, BDIM), blk, 0, stream>>>(
      xTb, wbf, bq, bk, bv, qTb, kTb, vBb);
  attn_kernel<<<dim3(NDIM / 512, BDIM * HDIM, NSPLIT), dim3(1024), 0, stream>>>(
      qTb, kTb, vBb, Opart, Lp);
  projout_kernel<<<dim3(NDIM / 64, 2, BDIM), blk, 0, stream>>>(
      Opart, Lp, wbf, bp, x, out);
}

// Round 16
// 191.944 us; speedup vs baseline: 1.0223x; 1.0184x over previous
//
#include <hip/hip_runtime.h>

// Attention_72902774882333 — R25: LOCK-IN of R23 (best measured config).
// R24 kill-criterion fired: conflict counter unchanged (8.585M) under V-layout
// swap -> conflicts are the structural 8-lanes-per-16B-column floor of b128
// reads on 128B rows (swizzle permutes colliders, can't reduce count); fixing
// needs padded rows => ds_write staging => measured -6µs net loss vs gload_lds.
// Session ledger: gload_lds (+16%), wave-width 4->8->16 (+6%), ones-MFMA l-sum,
// direct-W bf16 = the wins; pipeline/occupancy/NSPLIT/barrier/fusion = null.
// This file = R23 byte-identical. B=4, C=256, N=4096, H=4, DK=64.

#define BDIM 4
#define CDIM 256
#define NDIM 4096
#define HDIM 4
#define DKDIM 64
#define NQ   (BDIM * HDIM * NDIM)       // 65536
#define NSPLIT 2
#define KPERZ (NDIM / NSPLIT)           // 2048 keys per split
#define QSCALE 0.18033688011112042f     // log2(e)/8
#define WSZ (CDIM * CDIM)               // 65536 elems per weight matrix

typedef __bf16 bf16x8 __attribute__((ext_vector_type(8)));
typedef float f32x4 __attribute__((ext_vector_type(4)));
typedef short s16x4 __attribute__((ext_vector_type(4)));
typedef unsigned short u16;
typedef unsigned int u32;

__device__ __forceinline__ u16 f2bf(float f) {
  union { __bf16 h; u16 s; } u; u.h = (__bf16)f; return u.s;
}
__device__ __forceinline__ float bf2f(u16 v) {
  union { u32 u; float f; } x; x.u = (u32)v << 16; return x.f;
}
__device__ __forceinline__ u32 pk2(float a, float b) {
  return (u32)f2bf(a) | ((u32)f2bf(b) << 16);
}
__device__ __forceinline__ void gload16(const u16* g, u16* l) {
  __builtin_amdgcn_global_load_lds(
      (const __attribute__((address_space(1))) void*)g,
      (__attribute__((address_space(3))) void*)l, 16, 0, 0);
}

// ---------------- weight conversion: fp32 -> bf16, once ----------------
// wb layout: [4][WSZ] = wq(scaled), wk, wv, wp. Grid (32, 4).
__global__ __launch_bounds__(256) void wconv_kernel(
    const float* __restrict__ wq, const float* __restrict__ wk,
    const float* __restrict__ wv, const float* __restrict__ wp,
    u16* __restrict__ wb)
{
  const int a = blockIdx.y;
  const float* src = (a == 0) ? wq : (a == 1) ? wk : (a == 2) ? wv : wp;
  const float sc = (a == 0) ? QSCALE : 1.0f;
  const int i = (blockIdx.x * 256 + threadIdx.x) * 8;
  const float4 v0 = *(const float4*)(src + i);
  const float4 v1 = *(const float4*)(src + i + 4);
  union { u32 p[4]; uint4 q; } o;
  o.p[0] = pk2(v0.x * sc, v0.y * sc);
  o.p[1] = pk2(v0.z * sc, v0.w * sc);
  o.p[2] = pk2(v1.x * sc, v1.y * sc);
  o.p[3] = pk2(v1.z * sc, v1.w * sc);
  *(uint4*)(wb + (size_t)a * WSZ + i) = o.q;
}

// ---------------- x transpose: fp32 [b][c][n] -> bf16 [b][n][256] ----------------
__global__ __launch_bounds__(256) void xt_kernel(
    const float* __restrict__ x, u16* __restrict__ xT)
{
  const int b = blockIdx.z, c0 = blockIdx.y * 64, n0 = blockIdx.x * 64;
  __shared__ __align__(16) float T[64][68];
  const int t = threadIdx.x;
  {
    const int cr = t >> 4, nc = (t & 15) * 4;
    #pragma unroll
    for (int ci = 0; ci < 4; ++ci) {
      const float4 v = *(const float4*)&x[((size_t)(b * CDIM + c0 + cr + ci * 16)) * NDIM + n0 + nc];
      *(float4*)&T[cr + ci * 16][nc] = v;
    }
  }
  __syncthreads();
  {
    const int n = t >> 2, g = t & 3;
    union { u16 u[16]; uint4 v[2]; } pk;
    #pragma unroll
    for (int u_ = 0; u_ < 16; ++u_) pk.u[u_] = f2bf(T[g * 16 + u_][n]);
    uint4* dst = (uint4*)&xT[((size_t)(b * NDIM + n0 + n)) * CDIM + c0 + g * 16];
    dst[0] = pk.v[0]; dst[1] = pk.v[1];
  }
}

// ---------------- fused Q/K/V projection: full-tile staging, ONE barrier ----------------
// Grid (NDIM/64, 6, BDIM): p = y>>1, o0 = (y&1)*128.
__global__ __launch_bounds__(256, 4) void qkv_kernel(
    const u16* __restrict__ xT, const u16* __restrict__ wb,
    const float* __restrict__ bq, const float* __restrict__ bk,
    const float* __restrict__ bv,
    u16* __restrict__ qT, u16* __restrict__ kT, u16* __restrict__ vB)
{
  const int b = blockIdx.z;
  const int p = blockIdx.y >> 1;
  const int o0 = (blockIdx.y & 1) * 128;
  const int n0 = blockIdx.x * 64;
  const float* bsel = (p == 0) ? bq : (p == 1) ? bk : bv;
  const float wscale = (p == 0) ? QSCALE : 1.0f;

  __shared__ __align__(16) u16 XTs[64][264];   // 528B rows: 16B-aligned
  const int t = threadIdx.x, lane = t & 63, w = t >> 6;
  const int qd = lane >> 4, lm = lane & 15;
  const int sr = t >> 2, sg = (t & 3) * 8;

  // stage the whole 64x256 X tile once (8 coalesced uint4 loads/thread)
  {
    const u16* xsrc = xT + ((size_t)(b * NDIM + n0 + sr)) * CDIM + sg;
    #pragma unroll
    for (int cs = 0; cs < 8; ++cs)
      *(uint4*)&XTs[sr][cs * 32 + sg] = *(const uint4*)(xsrc + cs * 32);
  }
  __syncthreads();

  const u16* wrow0 = wb + (size_t)p * WSZ + (size_t)(o0 + 32 * w + lm) * CDIM + qd * 8;
  const u16* wrow1 = wrow0 + (size_t)16 * CDIM;

  f32x4 acc[4][2];
  #pragma unroll
  for (int nt = 0; nt < 4; ++nt)
    #pragma unroll
    for (int j = 0; j < 2; ++j) acc[nt][j] = (f32x4){0.f, 0.f, 0.f, 0.f};

  #pragma unroll
  for (int cs = 0; cs < 8; ++cs) {
    const bf16x8 wf0 = *(const bf16x8*)(wrow0 + cs * 32);
    const bf16x8 wf1 = *(const bf16x8*)(wrow1 + cs * 32);
    bf16x8 xf[4];
    #pragma unroll
    for (int nt = 0; nt < 4; ++nt)
      xf[nt] = *(const bf16x8*)&XTs[16 * nt + lm][cs * 32 + qd * 8];
    #pragma unroll
    for (int nt = 0; nt < 4; ++nt) {
      if (p < 2) {
        acc[nt][0] = __builtin_amdgcn_mfma_f32_16x16x32_bf16(xf[nt], wf0, acc[nt][0], 0, 0, 0);
        acc[nt][1] = __builtin_amdgcn_mfma_f32_16x16x32_bf16(xf[nt], wf1, acc[nt][1], 0, 0, 0);
      } else {
        acc[nt][0] = __builtin_amdgcn_mfma_f32_16x16x32_bf16(wf0, xf[nt], acc[nt][0], 0, 0, 0);
        acc[nt][1] = __builtin_amdgcn_mfma_f32_16x16x32_bf16(wf1, xf[nt], acc[nt][1], 0, 0, 0);
      }
    }
  }

  if (p < 2) {
    // D[m=n][col=o]: n = n0+16nt+4qd+r, o = o0+32w+16j+lm
    u16* out = (p == 0) ? qT : kT;
    #pragma unroll
    for (int j = 0; j < 2; ++j) {
      const int og = o0 + 32 * w + 16 * j + lm;
      const float bv2 = bsel[og] * wscale;
      #pragma unroll
      for (int nt = 0; nt < 4; ++nt)
        #pragma unroll
        for (int r = 0; r < 4; ++r) {
          const int n = n0 + 16 * nt + 4 * qd + r;
          out[((size_t)(b * NDIM + n)) * CDIM + og] = f2bf(acc[nt][j][r] + bv2);
        }
    }
  } else {
    // D[m=o][col=n]: o = o0+32w+16j+4qd+r, n = n0+16nt+lm
    #pragma unroll
    for (int j = 0; j < 2; ++j) {
      const float4 b4 = *(const float4*)&bsel[o0 + 32 * w + 16 * j + 4 * qd];
      const float bvr[4] = {b4.x, b4.y, b4.z, b4.w};
      #pragma unroll
      for (int nt = 0; nt < 4; ++nt)
        #pragma unroll
        for (int r = 0; r < 4; ++r) {
          const int og = o0 + 32 * w + 16 * j + 4 * qd + r;
          const int n = n0 + 16 * nt + lm;
          vB[((size_t)(b * CDIM + og)) * NDIM + n] = f2bf(acc[nt][j][r] + bvr[r]);
        }
    }
  }
}

// ---------------- K-split(2) flash attention: 1024 threads, 16 waves, 512 q-rows ----------------
// Per-wave structure identical to R22. Grid (NDIM/512, 16, NSPLIT) = 256 blocks
// = 1/CU x 16 waves. Staging: waves 0-7 stage K rows 8w..+8, waves 8-15 stage
// V rows 8(w-8)..+8 (one gload16 per wave).
__global__ __launch_bounds__(1024, 2) void attn_kernel(
    const u16* __restrict__ qT, const u16* __restrict__ kT,
    const u16* __restrict__ vB, u16* __restrict__ Opart,
    float* __restrict__ Lp)
{
  const int bh = blockIdx.y, b = bh >> 2, h = bh & 3;
  const int n0 = blockIdx.x * 512;
  const int z  = blockIdx.z;

  // [buf][0]=K tile, [buf][1]=V tile. 2*2*64*64*2B = 32768 B.
  __shared__ __align__(16) u16 KVlds[2][2][64][64];

  const int t = threadIdx.x, lane = t & 63, w = t >> 6;   // w in 0..15
  const int qd = lane >> 4, lm = lane & 15, l7 = lm & 7;

  // Q fragments straight from global: wave w owns q-rows 16*(2w+s)+lm.
  bf16x8 qf[2][2];
  {
    const u16* qbase = qT + ((size_t)(b * NDIM) + n0) * CDIM + h * 64;
    #pragma unroll
    for (int s = 0; s < 2; ++s)
      #pragma unroll
      for (int hh = 0; hh < 2; ++hh)
        qf[s][hh] = *(const bf16x8*)(qbase +
            (size_t)(16 * (2 * w + s) + lm) * CDIM + 32 * hh + qd * 8);
  }

  // ones A-fragment for the l-sum MFMA (bf16 1.0 = 0x3F80)
  const s16x4 ones = (s16x4){(short)0x3F80, (short)0x3F80, (short)0x3F80, (short)0x3F80};
  f32x4 la[2];
  la[0] = (f32x4){0.f, 0.f, 0.f, 0.f};
  la[1] = (f32x4){0.f, 0.f, 0.f, 0.f};

  f32x4 oa[2][4];
  #pragma unroll
  for (int s = 0; s < 2; ++s)
    #pragma unroll
    for (int dt = 0; dt < 4; ++dt) oa[s][dt] = (f32x4){0.f, 0.f, 0.f, 0.f};

  // staging: sw = w&7 covers tile rows 8*sw..+8; lane -> row 8*sw+(lane>>3),
  // 16B granule (lane&7), source granule pre-swizzled: ^(row&7) = ^(lane>>3).
  const int sw = w & 7;
  const int srow = lane >> 3;
  const int swz  = 8 * ((lane & 7) ^ srow);       // elems
  const u16* kp0 = kT + ((size_t)(b * NDIM + z * KPERZ + 8 * sw + srow)) * CDIM + h * 64 + swz;
  const u16* vp0 = vB + ((size_t)(b * CDIM + h * 64 + 8 * sw + srow)) * NDIM + z * KPERZ + swz;

  // prologue: stage tile 0 into buf 0 (one gload16 per wave)
  if (w < 8) gload16(kp0, &KVlds[0][0][0][0] + sw * 512);
  else       gload16(vp0, &KVlds[0][1][0][0] + sw * 512);

  #pragma unroll 1
  for (int it = 0; it < KPERZ / 64; ++it) {
    __syncthreads();   // vmcnt(0) drain: tile 'it' landed; all waves synced
    if (it + 1 < KPERZ / 64) {
      const size_t ko = (size_t)(it + 1) * 64 * CDIM;
      const int    vo = (it + 1) * 64;
      if (w < 8) gload16(kp0 + ko, &KVlds[(it + 1) & 1][0][0][0] + sw * 512);
      else       gload16(vp0 + vo, &KVlds[(it + 1) & 1][1][0][0] + sw * 512);
    }
    const u16 (*Kt)[64] = KVlds[it & 1][0];
    const u16 (*Vt)[64] = KVlds[it & 1][1];

    // P fragments, packed bf16 at production: pk[s][c].v is the PV B-operand
    union { u16 u[4]; u32 d[2]; s16x4 v; } pk[2][4];

    #pragma unroll
    for (int nt = 0; nt < 4; ++nt) {
      // swizzled read: granule (4hh+qd) ^ (row&7), row&7 == lm&7
      const bf16x8 kf0 = *(const bf16x8*)&Kt[16 * nt + lm][8 * (qd ^ l7)];
      const bf16x8 kf1 = *(const bf16x8*)&Kt[16 * nt + lm][8 * ((4 + qd) ^ l7)];
      #pragma unroll
      for (int s = 0; s < 2; ++s) {
        f32x4 zz = (f32x4){0.f, 0.f, 0.f, 0.f};
        zz = __builtin_amdgcn_mfma_f32_16x16x32_bf16(kf0, qf[s][0], zz, 0, 0, 0);
        zz = __builtin_amdgcn_mfma_f32_16x16x32_bf16(kf1, qf[s][1], zz, 0, 0, 0);
        const float p0 = __builtin_amdgcn_exp2f(zz[0]);
        const float p1 = __builtin_amdgcn_exp2f(zz[1]);
        const float p2 = __builtin_amdgcn_exp2f(zz[2]);
        const float p3 = __builtin_amdgcn_exp2f(zz[3]);
        pk[s][nt].d[0] = pk2(p0, p1);
        pk[s][nt].d[1] = pk2(p2, p3);
      }
    }

    #pragma unroll
    for (int c = 0; c < 4; ++c) {
      s16x4 av[4];
      #pragma unroll
      for (int dt = 0; dt < 4; ++dt)
        av[dt] = *(const s16x4*)&Vt[16 * dt + lm][(16 * c + 4 * qd) ^ (8 * l7)];
      // l-sum on the MFMA pipe: every output row = sum_k P[k][q], col q = lm
      la[0] = __builtin_amdgcn_mfma_f32_16x16x16bf16_1k(ones, pk[0][c].v, la[0], 0, 0, 0);
      la[1] = __builtin_amdgcn_mfma_f32_16x16x16bf16_1k(ones, pk[1][c].v, la[1], 0, 0, 0);
      #pragma unroll
      for (int dt = 0; dt < 4; ++dt) {
        oa[0][dt] = __builtin_amdgcn_mfma_f32_16x16x16bf16_1k(av[dt], pk[0][c].v, oa[0][dt], 0, 0, 0);
        oa[1][dt] = __builtin_amdgcn_mfma_f32_16x16x16bf16_1k(av[dt], pk[1][c].v, oa[1][dt], 0, 0, 0);
      }
    }
  }

  // la[s][r] identical across r and across qd quads: full l for q = lm.
  const float l_i[2] = {la[0][0], la[1][0]};

  if (qd == 0) {
    const size_t lbase = ((size_t)z * (BDIM * HDIM) + bh) * NDIM;
    #pragma unroll
    for (int s = 0; s < 2; ++s)
      Lp[lbase + n0 + 16 * (2 * w + s) + lm] = l_i[s];
  }

  __syncthreads();   // all waves done reading the last tile before overlay
  // epilogue: normalize + transpose via LDS overlay in FOUR phases of 128 rows.
  u16 (*Ot)[72] = (u16(*)[72])&KVlds[0][0][0][0];   // [128][72] = 18432B fits
  #pragma unroll
  for (int ph = 0; ph < 4; ++ph) {
    if ((w >> 2) == ph) {
      const int wl = w & 3;
      #pragma unroll
      for (int s = 0; s < 2; ++s) {
        const float inv = 1.0f / l_i[s];
        #pragma unroll
        for (int dt = 0; dt < 4; ++dt)
          #pragma unroll
          for (int r = 0; r < 4; ++r)
            Ot[16 * (2 * wl + s) + lm][16 * dt + 4 * qd + r] = f2bf(oa[s][dt][r] * inv);
      }
    }
    __syncthreads();
    {
      const int r = t >> 3, g = (t & 7) * 8;   // 1024 thr x 16B = 128 rows x 128B
      u16* dst = Opart + (((size_t)z * (BDIM * HDIM) + bh) * NDIM + n0 + ph * 128 + r) * DKDIM + g;
      *(uint4*)dst = *(const uint4*)&Ot[r][g];
    }
    __syncthreads();
  }
}

// ---------------- output projection, W direct-from-global bf16, 2-way combine ----------------
// Grid (NDIM/64, 2, BDIM). Combine weights = l ratios (shift-free partials).
__global__ __launch_bounds__(256, 4) void projout_kernel(
    const u16* __restrict__ Opart, const float* __restrict__ Lp,
    const u16* __restrict__ wb, const float* __restrict__ bp,
    const float* __restrict__ res, float* __restrict__ out)
{
  const int b = blockIdx.z, o0 = blockIdx.y * 128, n0 = blockIdx.x * 64;
  __shared__ __align__(16) u16 XTs[64][40];
  const int t = threadIdx.x, lane = t & 63, w = t >> 6;
  const int qd = lane >> 4, lm = lane & 15;
  const int sr = t >> 2, sg = (t & 3) * 8;

  float wh[4][NSPLIT];
  #pragma unroll
  for (int hh = 0; hh < 4; ++hh) {
    const size_t i0 = ((size_t)(b * HDIM + hh)) * NDIM + n0 + sr;
    float l[NSPLIT], tot = 0.f;
    #pragma unroll
    for (int zz = 0; zz < NSPLIT; ++zz) { l[zz] = Lp[(size_t)zz * NQ + i0]; tot += l[zz]; }
    const float iv = 1.0f / tot;
    #pragma unroll
    for (int zz = 0; zz < NSPLIT; ++zz) wh[hh][zz] = l[zz] * iv;
  }

  const u16* wrow0 = wb + (size_t)3 * WSZ + (size_t)(o0 + 32 * w + lm) * CDIM + qd * 8;
  const u16* wrow1 = wrow0 + (size_t)16 * CDIM;

  f32x4 acc[4][2];
  #pragma unroll
  for (int nt = 0; nt < 4; ++nt)
    #pragma unroll
    for (int j = 0; j < 2; ++j) acc[nt][j] = (f32x4){0.f, 0.f, 0.f, 0.f};

  for (int cs = 0; cs < 8; ++cs) {
    const int c0 = cs * 32;
    const int hh = c0 >> 6;
    const int dk = (c0 & 63) + sg;
    const bf16x8 wf0 = *(const bf16x8*)(wrow0 + c0);
    const bf16x8 wf1 = *(const bf16x8*)(wrow1 + c0);
    __syncthreads();
    {
      const size_t obase = (((size_t)(b * HDIM + hh)) * NDIM + n0 + sr) * DKDIM + dk;
      float v[8] = {0.f, 0.f, 0.f, 0.f, 0.f, 0.f, 0.f, 0.f};
      #pragma unroll
      for (int zz = 0; zz < NSPLIT; ++zz) {
        union { u16 u[8]; uint4 q; } a;
        a.q = *(const uint4*)(Opart + (size_t)zz * NQ * DKDIM + obase);
        const float wz = wh[hh][zz];
        #pragma unroll
        for (int j = 0; j < 8; ++j) v[j] = fmaf(wz, bf2f(a.u[j]), v[j]);
      }
      union { u16 u[8]; uint4 q; } ov;
      #pragma unroll
      for (int j = 0; j < 8; ++j) ov.u[j] = f2bf(v[j]);
      *(uint4*)&XTs[sr][sg] = ov.q;
    }
    __syncthreads();
    bf16x8 xf[4];
    #pragma unroll
    for (int nt = 0; nt < 4; ++nt) xf[nt] = *(const bf16x8*)&XTs[16 * nt + lm][qd * 8];
    #pragma unroll
    for (int nt = 0; nt < 4; ++nt) {
      acc[nt][0] = __builtin_amdgcn_mfma_f32_16x16x32_bf16(wf0, xf[nt], acc[nt][0], 0, 0, 0);
      acc[nt][1] = __builtin_amdgcn_mfma_f32_16x16x32_bf16(wf1, xf[nt], acc[nt][1], 0, 0, 0);
    }
  }

  // D[m=o][col=n]: o = o0+32w+16j+4qd+r, n = n0+16nt+lm
  #pragma unroll
  for (int j = 0; j < 2; ++j) {
    const float4 b4 = *(const float4*)&bp[o0 + 32 * w + 16 * j + 4 * qd];
    const float bvr[4] = {b4.x, b4.y, b4.z, b4.w};
    #pragma unroll
    for (int nt = 0; nt < 4; ++nt)
      #pragma unroll
      for (int r = 0; r < 4; ++r) {
        const int og = o0 + 32 * w + 16 * j + 4 * qd + r;
        const int n = n0 + 16 * nt + lm;
        const size_t idx = ((size_t)(b * CDIM + og)) * NDIM + n;
        out[idx] = acc[nt][j][r] + bvr[r] + res[idx];
      }
  }
}

extern "C" void kernel_launch(void* const* d_in, const int* in_sizes, int n_in,
                              void* d_out, int out_size, void* d_ws, size_t ws_size,
                              hipStream_t stream)
{
  const float* x  = (const float*)d_in[0];
  const float* wq = (const float*)d_in[1];
  const float* bq = (const float*)d_in[2];
  const float* wk = (const float*)d_in[3];
  const float* bk = (const float*)d_in[4];
  const float* wv = (const float*)d_in[5];
  const float* bv = (const float*)d_in[6];
  const float* wp = (const float*)d_in[7];
  const float* bp = (const float*)d_in[8];
  float* out = (float*)d_out;

  const size_t sz = (size_t)BDIM * CDIM * NDIM;   // 4.19M elements
  u16* xTb = (u16*)d_ws;
  u16* qTb = xTb + sz;
  u16* kTb = qTb + sz;
  u16* vBb = kTb + sz;
  u16* Opart = vBb + sz;                          // NSPLIT*sz u16
  float* Lp = (float*)(Opart + (size_t)NSPLIT * sz);  // NSPLIT*NQ floats
  u16* wbf = (u16*)(Lp + (size_t)NSPLIT * NQ);    // 4*WSZ u16 (512KB)

  const dim3 blk(256);
  wconv_kernel<<<dim3(WSZ / (256 * 8), 4, 1), blk, 0, stream>>>(wq, wk, wv, wp, wbf);
  xt_kernel<<<dim3(NDIM / 64, CDIM / 64, BDIM), blk, 0, stream>>>(x, xTb);
  qkv_kernel<<<dim3(NDIM / 64, 6, BDIM), blk, 0, stream>>>(
      xTb, wbf, bq, bk, bv, qTb, kTb, vBb);
  attn_kernel<<<dim3(NDIM / 512, BDIM * HDIM, NSPLIT), dim3(1024), 0, stream>>>(
      qTb, kTb, vBb, Opart, Lp);
  projout_kernel<<<dim3(NDIM / 64, 2, BDIM), blk, 0, stream>>>(
      Opart, Lp, wbf, bp, x, out);
}